// Round 6
// baseline (801.674 us; speedup 1.0000x reference)
//
#include <hip/hip_runtime.h>
#include <math.h>

#define NB 32
#define ND 768
#define NS 196
#define NL 77

typedef __bf16 bf16x8 __attribute__((ext_vector_type(8)));
typedef float f32x4 __attribute__((ext_vector_type(4)));

__device__ __forceinline__ f32x4 mfma16(bf16x8 a, bf16x8 b, f32x4 c) {
  return __builtin_amdgcn_mfma_f32_16x16x32_bf16(a, b, c, 0, 0, 0);
}

// ===================== prep_all: tx-fragments | ctx transpose (LDS, coalesced) | lens+norms =====================
__global__ __launch_bounds__(256) void prep_all_kernel(
    const float* __restrict__ text_local,
    const float* __restrict__ img_local,
    const float* __restrict__ img_global,
    const float* __restrict__ text_global,
    const int* __restrict__ amask,
    __bf16* __restrict__ txf,
    __bf16* __restrict__ cTh, __bf16* __restrict__ cTl,
    float* __restrict__ n1ws, int* __restrict__ lenws,
    float* __restrict__ invni, float* __restrict__ invnt) {
  const int bid = blockIdx.x;
  const int t = threadIdx.x;
  __shared__ float tile[64][213];  // transpose staging (54.5 KB)

  if (bid < 960) {
    // ---- text fragments: txf[i][dk][lt][pl][lane][8] ----
    int tau = bid * 256 + t;            // 32*24*5*64
    int i = tau / 7680;
    int r = tau - i * 7680;
    int dk = r / 320;
    int r2 = r - dk * 320;
    int lt = r2 >> 6, lane = r2 & 63;
    int n16 = lane & 15, g = lane >> 4;
    int l = lt * 16 + n16;
    float v[8];
#pragma unroll
    for (int q = 0; q < 8; ++q) v[q] = 0.f;
    if (l < NL) {
      const float* src = text_local + ((size_t)i * NL + l) * ND + dk * 32 + g * 8;
      float4 a = *(const float4*)src;
      float4 b = *(const float4*)(src + 4);
      v[0] = a.x; v[1] = a.y; v[2] = a.z; v[3] = a.w;
      v[4] = b.x; v[5] = b.y; v[6] = b.z; v[7] = b.w;
    }
    bf16x8 hv, lv;
#pragma unroll
    for (int q = 0; q < 8; ++q) {
      __bf16 h = (__bf16)v[q];
      hv[q] = h;
      lv[q] = (__bf16)(v[q] - (float)h);
    }
    size_t base = ((((size_t)i * 24 + dk) * 5 + lt) * 2) * 512 + (size_t)lane * 8;
    *(bf16x8*)(txf + base) = hv;
    *(bf16x8*)(txf + base + 512) = lv;
  } else if (bid < 1344) {
    // ---- ctx transpose via LDS: coalesced reads along s ----
    const int b2 = bid - 960;
    const int j = b2 / 12, dc = b2 - (b2 / 12) * 12;
    const float* src = img_local + ((size_t)j * ND + dc * 64) * NS;
    for (int idx = t; idx < 3136; idx += 256) {  // 64 rows * 49 float4
      int dd = idx / 49, sq = idx - dd * 49;
      float4 v = *(const float4*)(src + (size_t)dd * NS + sq * 4);
      tile[dd][sq * 4 + 0] = v.x;
      tile[dd][sq * 4 + 1] = v.y;
      tile[dd][sq * 4 + 2] = v.z;
      tile[dd][sq * 4 + 3] = v.w;
    }
    __syncthreads();
    for (int idx = t; idx < 1664; idx += 256) {  // 208 s * 8 octets
      int o = idx & 7, s = idx >> 3;
      bf16x8 hv, lv;
#pragma unroll
      for (int q = 0; q < 8; ++q) {
        float v = (s < NS) ? tile[o * 8 + q][s] : 0.f;
        __bf16 h = (__bf16)v;
        hv[q] = h;
        lv[q] = (__bf16)(v - (float)h);
      }
      size_t off = ((size_t)j * 208 + s) * ND + dc * 64 + o * 8;
      *(bf16x8*)(cTh + off) = hv;
      *(bf16x8*)(cTl + off) = lv;
    }
  } else {
    // ---- lengths + word norms + global-vector norms ----
    const int i = bid - 1344;
    const int lane = t & 63, w = t >> 6;
    __shared__ int slen;
    if (t == 0) slen = 0;
    __syncthreads();
    if (t < NL && amask[i * NL + t] != 0) atomicAdd(&slen, 1);
    for (int l = w; l < NL; l += 4) {
      const float4* p = (const float4*)(text_local + ((size_t)i * NL + l) * ND);
      float s = 0.f;
#pragma unroll
      for (int k = 0; k < 3; ++k) {
        float4 v = p[lane + 64 * k];
        s += v.x * v.x + v.y * v.y + v.z * v.z + v.w * v.w;
      }
#pragma unroll
      for (int off = 32; off; off >>= 1) s += __shfl_xor(s, off);
      if (lane == 0) n1ws[i * 80 + l] = sqrtf(s);
    }
    if (w < 2) {
      const float* src2 = (w == 0) ? (img_global + (size_t)i * ND)
                                   : (text_global + (size_t)i * ND);
      const float4* p = (const float4*)src2;
      float s = 0.f;
#pragma unroll
      for (int k = 0; k < 3; ++k) {
        float4 v = p[lane + 64 * k];
        s += v.x * v.x + v.y * v.y + v.z * v.z + v.w * v.w;
      }
#pragma unroll
      for (int off = 32; off; off >>= 1) s += __shfl_xor(s, off);
      if (lane == 0) {
        float inv = 1.0f / fmaxf(sqrtf(s), 1e-12f);
        if (w == 0) invni[i] = inv; else invnt[i] = inv;
      }
    }
    __syncthreads();
    if (t == 0) lenws[i] = slen;
  }
}

// ===================== per-image Gram G = ctx^T ctx, bf16 hi/lo [208][224], col-split =====================
__global__ void gram_kernel(const __bf16* __restrict__ cTh, const __bf16* __restrict__ cTl,
                            __bf16* __restrict__ Ghp, __bf16* __restrict__ Glp) {
  const int bid = blockIdx.x;  // 32 j * 13 st * 2 ch = 832
  const int j = bid / 26;
  const int rr = bid - j * 26;
  const int st = rr >> 1, ch = rr & 1;
  const int t = threadIdx.x, lane = t & 63, w = t >> 6;
  const int g = lane >> 4, n16 = lane & 15;
  const size_t cb = (size_t)j * 208;
  const f32x4 z4 = {0.f, 0.f, 0.f, 0.f};
  f32x4 accG[2];
  accG[0] = z4; accG[1] = z4;
  const int base = ch * 7;
  const int ncols = ch ? 6 : 7;
  const size_t aoff = (cb + st * 16 + n16) * ND + g * 8;
  for (int dk = 0; dk < 24; ++dk) {
    bf16x8 Ah = *(const bf16x8*)(cTh + aoff + dk * 32);
    bf16x8 Al = *(const bf16x8*)(cTl + aoff + dk * 32);
#pragma unroll
    for (int q = 0; q < 2; ++q) {
      int ntl = w + (q << 2);
      if (ntl < ncols) {
        int nt = base + ntl;
        size_t boff = (cb + nt * 16 + n16) * ND + dk * 32 + g * 8;
        bf16x8 Bh = *(const bf16x8*)(cTh + boff);
        bf16x8 Bl = *(const bf16x8*)(cTl + boff);
        accG[q] = mfma16(Ah, Bh, accG[q]);
        accG[q] = mfma16(Ah, Bl, accG[q]);
        accG[q] = mfma16(Al, Bh, accG[q]);
      }
    }
  }
#pragma unroll
  for (int q = 0; q < 2; ++q) {
    int ntl = w + (q << 2);
    int nt = base + ntl;
    bool compute = (ntl < ncols);
    bool zfill = (ch == 1 && nt == 13);
    if (compute || zfill) {
#pragma unroll
      for (int r = 0; r < 4; ++r) {
        int s = st * 16 + g * 4 + r;
        int col = nt * 16 + n16;
        float v = compute ? accG[q][r] : 0.f;
        __bf16 hi = (__bf16)v;
        __bf16 lo = (__bf16)(v - (float)hi);
        size_t o = ((size_t)j * 208 + s) * 224 + col;
        Ghp[o] = hi;
        Glp[o] = lo;
      }
    }
  }
}

// ===================== global contrastive scores =====================
__global__ void gsc_kernel(const float* __restrict__ img_global,
                           const float* __restrict__ text_global,
                           const float* __restrict__ invni,
                           const float* __restrict__ invnt,
                           float* __restrict__ gscw) {
  const int a = blockIdx.x;
  const int t = threadIdx.x;
  const int lane = t & 63;
  const int w = t >> 6;
  __shared__ __align__(16) float shi[ND];
  if (t < ND / 4) ((float4*)shi)[t] = ((const float4*)(img_global + (size_t)a * ND))[t];
  __syncthreads();
  for (int b = w; b < NB; b += 4) {
    const float4* pt = (const float4*)(text_global + (size_t)b * ND);
    const float4* pi = (const float4*)shi;
    float s = 0.f;
#pragma unroll
    for (int k = 0; k < 3; ++k) {
      float4 x = pi[lane + 64 * k];
      float4 y = pt[lane + 64 * k];
      s += x.x * y.x + x.y * y.y + x.z * y.z + x.w * y.w;
    }
#pragma unroll
    for (int off = 32; off; off >>= 1) s += __shfl_xor(s, off);
    if (lane == 0) gscw[a * NB + b] = s * invni[a] * invnt[b] * 10.0f;
  }
}

// ===================== per-pair fused local loss: barrier-free + reg double-buffer =====================
__global__ __launch_bounds__(256, 3) void pair_kernel(
    const __bf16* __restrict__ txf,
    const __bf16* __restrict__ cTh, const __bf16* __restrict__ cTl,
    const __bf16* __restrict__ Ghp, const __bf16* __restrict__ Glp,
    const float* __restrict__ n1ws, const int* __restrict__ lenws,
    float* __restrict__ simws) {
  const int t = threadIdx.x;
  // XCD swizzle: 1024 % 8 == 0 -> bijective
  const int wg = ((blockIdx.x & 7) << 7) + (blockIdx.x >> 3);
  const int j = wg >> 5, i = wg & 31;
  const int len = lenws[i];
  const int nlt = (len + 15) >> 4;
  const int lane = t & 63, w = t >> 6;
  const int g = lane >> 4, n16 = lane & 15;

  __shared__ __align__(16) __bf16 e2f[7 * 5 * 64 * 8];  // 35840 B
  __shared__ float w12s[80], z2s[80], n2s[80];

  for (int idx = t; idx < 2240; idx += 256)
    ((uint4*)e2f)[idx] = make_uint4(0, 0, 0, 0);
  if (t < 80) { w12s[t] = 0.f; z2s[t] = 0.f; n2s[t] = 0.f; }
  __syncthreads();

  const size_t arow = (size_t)j * 208;
  const __bf16* txi = txf + (size_t)i * 24 * 5 * 2 * 512 + (lane << 3);
  const f32x4 z4 = {0.f, 0.f, 0.f, 0.f};

  float w12loc[5], z2loc[5];
#pragma unroll
  for (int lt = 0; lt < 5; ++lt) { w12loc[lt] = 0.f; z2loc[lt] = 0.f; }

  bf16x8 cAh[2][2], cAl[2][2];
  bf16x8 cBh[2][5], cBl[2][5];

#define LOADA(B, DK)                                                    \
  do {                                                                  \
    size_t o0 = aoff0 + (size_t)(DK) * 32;                              \
    cAh[B][0] = *(const bf16x8*)(cTh + o0);                             \
    cAl[B][0] = *(const bf16x8*)(cTl + o0);                             \
    if (v1) {                                                           \
      size_t o1 = aoff1 + (size_t)(DK) * 32;                            \
      cAh[B][1] = *(const bf16x8*)(cTh + o1);                           \
      cAl[B][1] = *(const bf16x8*)(cTl + o1);                           \
    }                                                                   \
  } while (0)

#define LOADB(B, DK)                                                    \
  do {                                                                  \
    _Pragma("unroll")                                                   \
    for (int lt = 0; lt < 5; ++lt)                                      \
      if (lt < nlt) {                                                   \
        const __bf16* bp = txi + (((size_t)(DK) * 5 + lt) << 10);       \
        cBh[B][lt] = *(const bf16x8*)bp;                                \
        cBl[B][lt] = *(const bf16x8*)(bp + 512);                        \
      }                                                                 \
  } while (0)

#define MFMAS(B)                                                        \
  do {                                                                  \
    __builtin_amdgcn_s_setprio(1);                                      \
    _Pragma("unroll")                                                   \
    for (int lt = 0; lt < 5; ++lt)                                      \
      if (lt < nlt) {                                                   \
        acc[0][lt] = mfma16(cAh[B][0], cBh[B][lt], acc[0][lt]);         \
        acc[0][lt] = mfma16(cAh[B][0], cBl[B][lt], acc[0][lt]);         \
        acc[0][lt] = mfma16(cAl[B][0], cBh[B][lt], acc[0][lt]);         \
        if (v1) {                                                       \
          acc[1][lt] = mfma16(cAh[B][1], cBh[B][lt], acc[1][lt]);       \
          acc[1][lt] = mfma16(cAh[B][1], cBl[B][lt], acc[1][lt]);       \
          acc[1][lt] = mfma16(cAl[B][1], cBh[B][lt], acc[1][lt]);       \
        }                                                               \
      }                                                                 \
    __builtin_amdgcn_s_setprio(0);                                      \
  } while (0)

  // ==== phases 1+2, two passes over S-tiles ====
#pragma unroll 1
  for (int pass = 0; pass < 2; ++pass) {
    const int S0 = w + 4 * (pass * 2);
    const int S1 = w + 4 * (pass * 2 + 1);
    const bool v1 = (S1 < 13);
    const size_t aoff0 = (arow + S0 * 16 + n16) * ND + g * 8;
    const size_t aoff1 = (arow + S1 * 16 + n16) * ND + g * 8;
    f32x4 acc[2][5];
#pragma unroll
    for (int q = 0; q < 2; ++q)
#pragma unroll
      for (int lt = 0; lt < 5; ++lt) acc[q][lt] = z4;

    // --- phase 1: software-pipelined split-bf16 MFMA, no barriers ---
    LOADA(0, 0);
    LOADB(0, 0);
#pragma unroll 1
    for (int dk = 0; dk < 24; dk += 2) {
      LOADA(1, dk + 1);
      LOADB(1, dk + 1);
      MFMAS(0);
      if (dk < 22) {
        LOADA(0, dk + 2);
        LOADB(0, dk + 2);
      }
      MFMAS(1);
    }

    // --- phase 2: register softmax over l, e2 = exp(4*a1), fold w12/Z2 ---
#pragma unroll
    for (int q = 0; q < 2; ++q) {
      const int S = (q == 0) ? S0 : S1;
      if (q == 0 || v1) {
#pragma unroll
        for (int r = 0; r < 4; ++r) {
          int s = S * 16 + g * 4 + r;
          bool srow = (s < NS);
          float m = -1e30f;
#pragma unroll
          for (int lt = 0; lt < 5; ++lt) {
            if (lt < nlt) {
              if ((lt * 16 + n16) < len) m = fmaxf(m, acc[q][lt][r]);
            }
          }
          m = fmaxf(m, __shfl_xor(m, 1));
          m = fmaxf(m, __shfl_xor(m, 2));
          m = fmaxf(m, __shfl_xor(m, 4));
          m = fmaxf(m, __shfl_xor(m, 8));
          float z = 0.f;
          float ev[5];
#pragma unroll
          for (int lt = 0; lt < 5; ++lt) {
            float e = 0.f;
            if (lt < nlt) {
              if ((lt * 16 + n16) < len) e = __expf(acc[q][lt][r] - m);
            }
            ev[lt] = e;
            z += e;
          }
          z += __shfl_xor(z, 1);
          z += __shfl_xor(z, 2);
          z += __shfl_xor(z, 4);
          z += __shfl_xor(z, 8);
          float inv = 4.0f / z;
#pragma unroll
          for (int lt = 0; lt < 5; ++lt) {
            if (lt < nlt) {
              if (((lt * 16 + n16) < len) && srow) {
                float e2 = __expf(ev[lt] * inv);
                w12loc[lt] += e2 * acc[q][lt][r];
                z2loc[lt] += e2;
                int kt = s >> 5, kk = s & 31;
                e2f[(((kt * 5) + lt) * 64 + (n16 + ((kk >> 3) << 4))) * 8 + (kk & 7)] = (__bf16)e2;
              }
            }
          }
        }
      }
    }
  }

  // fold w12/Z2
#pragma unroll
  for (int lt = 0; lt < 5; ++lt) {
    w12loc[lt] += __shfl_xor(w12loc[lt], 16);
    w12loc[lt] += __shfl_xor(w12loc[lt], 32);
    z2loc[lt] += __shfl_xor(z2loc[lt], 16);
    z2loc[lt] += __shfl_xor(z2loc[lt], 32);
  }
  if (lane < 16) {
#pragma unroll
    for (int lt = 0; lt < 5; ++lt) {
      if (lt < nlt) {
        atomicAdd(&w12s[lt * 16 + lane], w12loc[lt]);
        atomicAdd(&z2s[lt * 16 + lane], z2loc[lt]);
      }
    }
  }
  __syncthreads();  // e2f complete

  // ==== phase 3: n2^2 = e2^T G e2 via MFMA (kt-prefetch) ====
  const int nst = (w == 0) ? 4 : 3;
  float n2loc[5];
#pragma unroll
  for (int lt = 0; lt < 5; ++lt) n2loc[lt] = 0.f;
  const size_t gb = (size_t)j * 208;
#pragma unroll
  for (int q = 0; q < 4; ++q) {
    if (q < nst) {
      int S = w + (q << 2);
      f32x4 a2[5];
#pragma unroll
      for (int lt = 0; lt < 5; ++lt) a2[lt] = z4;
      const __bf16* gph = Ghp + (gb + S * 16 + n16) * 224 + g * 8;
      const __bf16* gpl = Glp + (gb + S * 16 + n16) * 224 + g * 8;
      bf16x8 GAh = *(const bf16x8*)gph;
      bf16x8 GAl = *(const bf16x8*)gpl;
#pragma unroll
      for (int kt = 0; kt < 7; ++kt) {
        bf16x8 GAhN, GAlN;
        if (kt < 6) {
          GAhN = *(const bf16x8*)(gph + (kt + 1) * 32);
          GAlN = *(const bf16x8*)(gpl + (kt + 1) * 32);
        }
        __builtin_amdgcn_s_setprio(1);
#pragma unroll
        for (int lt = 0; lt < 5; ++lt) {
          if (lt < nlt) {
            bf16x8 Bv = *(const bf16x8*)&e2f[(((kt * 5) + lt) * 64 + lane) * 8];
            a2[lt] = mfma16(GAh, Bv, a2[lt]);
            a2[lt] = mfma16(GAl, Bv, a2[lt]);
          }
        }
        __builtin_amdgcn_s_setprio(0);
        if (kt < 6) { GAh = GAhN; GAl = GAlN; }
      }
#pragma unroll
      for (int lt = 0; lt < 5; ++lt) {
        if (lt < nlt) {
#pragma unroll
          for (int r = 0; r < 4; ++r) {
            int s = S * 16 + g * 4 + r;
            int kt = s >> 5, kk = s & 31;
            float e2v = (float)e2f[(((kt * 5) + lt) * 64 + (n16 + ((kk >> 3) << 4))) * 8 + (kk & 7)];
            n2loc[lt] += e2v * a2[lt][r];
          }
        }
      }
    }
  }
#pragma unroll
  for (int lt = 0; lt < 5; ++lt) {
    n2loc[lt] += __shfl_xor(n2loc[lt], 16);
    n2loc[lt] += __shfl_xor(n2loc[lt], 32);
  }
  if (lane < 16) {
#pragma unroll
    for (int lt = 0; lt < 5; ++lt) {
      if (lt < nlt) atomicAdd(&n2s[lt * 16 + lane], n2loc[lt]);
    }
  }
  __syncthreads();

  // ==== epilogue: cosine + log-sum-exp ====
  if (t < len) {
    float z2 = z2s[t];
    float w12v = w12s[t] / z2;
    float n2v = sqrtf(n2s[t]) / z2;
    float n1v = n1ws[i * 80 + t];
    float cosv = w12v / fmaxf(n1v * n2v, 1e-8f);
    w12s[t] = __expf(5.0f * cosv);
  }
  __syncthreads();
  if (t == 0) {
    float sum = 0.f;
    for (int l = 0; l < len; ++l) sum += w12s[l];
    simws[i * NB + j] = __logf(sum);
  }
#undef LOADA
#undef LOADB
#undef MFMAS
}

// ===================== final cross-entropies =====================
__global__ void loss_kernel(const float* __restrict__ gscw,
                            const float* __restrict__ simws,
                            float* __restrict__ out) {
  const int t = threadIdx.x;
  __shared__ float gs[NB][NB];
  __shared__ float sl[NB][NB];
  __shared__ float parts[4][NB];
  {
    float4 gv = ((const float4*)gscw)[t];
    ((float4*)gs)[t] = gv;
    float4 v = ((const float4*)simws)[t];
    int ii = t >> 3;
    int j0 = (t & 7) * 4;
    sl[j0 + 0][ii] = v.x * 10.0f;
    sl[j0 + 1][ii] = v.y * 10.0f;
    sl[j0 + 2][ii] = v.z * 10.0f;
    sl[j0 + 3][ii] = v.w * 10.0f;
  }
  __syncthreads();
  if (t < NB) {
    float m, z;
    m = -1e30f;
    for (int c = 0; c < NB; ++c) m = fmaxf(m, gs[t][c]);
    z = 0.f;
    for (int c = 0; c < NB; ++c) z += __expf(gs[t][c] - m);
    parts[0][t] = m + __logf(z) - gs[t][t];

    m = -1e30f;
    for (int c = 0; c < NB; ++c) m = fmaxf(m, gs[c][t]);
    z = 0.f;
    for (int c = 0; c < NB; ++c) z += __expf(gs[c][t] - m);
    parts[1][t] = m + __logf(z) - gs[t][t];

    m = -1e30f;
    for (int c = 0; c < NB; ++c) m = fmaxf(m, sl[t][c]);
    z = 0.f;
    for (int c = 0; c < NB; ++c) z += __expf(sl[t][c] - m);
    parts[2][t] = m + __logf(z) - sl[t][t];

    m = -1e30f;
    for (int c = 0; c < NB; ++c) m = fmaxf(m, sl[c][t]);
    z = 0.f;
    for (int c = 0; c < NB; ++c) z += __expf(sl[c][t] - m);
    parts[3][t] = m + __logf(z) - sl[t][t];
  }
  __syncthreads();
  if (t == 0) {
    float s0 = 0.f, s1 = 0.f, s2 = 0.f, s3 = 0.f;
    for (int r = 0; r < NB; ++r) {
      s0 += parts[0][r]; s1 += parts[1][r];
      s2 += parts[2][r]; s3 += parts[3][r];
    }
    out[0] = 0.5f * (s0 + s1) / 32.0f + 0.5f * (s2 + s3) / 32.0f;
  }
}

extern "C" void kernel_launch(void* const* d_in, const int* in_sizes, int n_in,
                              void* d_out, int out_size, void* d_ws, size_t ws_size,
                              hipStream_t stream) {
  (void)in_sizes; (void)n_in; (void)out_size; (void)ws_size;
  const float* img_global  = (const float*)d_in[0];
  const float* img_local   = (const float*)d_in[1];
  const float* text_global = (const float*)d_in[2];
  const float* text_local  = (const float*)d_in[3];
  const int*   amask       = (const int*)d_in[4];

  __bf16* txf = (__bf16*)d_ws;                    // 32*24*5*2*512 = 3,932,160
  __bf16* cTh = txf + (size_t)3932160;            // 32*208*768 = 5,111,808
  __bf16* cTl = cTh + (size_t)5111808;
  __bf16* Ghp = cTl + (size_t)5111808;            // 32*208*224 = 1,490,944
  __bf16* Glp = Ghp + (size_t)1490944;
  float* fsm  = (float*)(Glp + (size_t)1490944);
  float* n1ws  = fsm;                              // [32][80]
  float* simws = fsm + 2560;                       // [32][32]
  float* gscw  = fsm + 3584;                       // [32][32]
  float* invni = fsm + 4608;                       // [32]
  float* invnt = fsm + 4640;                       // [32]
  int*   lenws = (int*)(fsm + 4672);               // [32]

  prep_all_kernel<<<1376, 256, 0, stream>>>(text_local, img_local, img_global,
                                            text_global, amask, txf, cTh, cTl,
                                            n1ws, lenws, invni, invnt);
  gram_kernel<<<832, 256, 0, stream>>>(cTh, cTl, Ghp, Glp);
  gsc_kernel<<<32, 256, 0, stream>>>(img_global, text_global, invni, invnt, gscw);
  pair_kernel<<<1024, 256, 0, stream>>>(txf, cTh, cTl, Ghp, Glp, n1ws, lenws, simws);
  loss_kernel<<<1, 256, 0, stream>>>(gscw, simws, (float*)d_out);
}

// Round 7
// 155.988 us; speedup vs baseline: 5.1393x; 5.1393x over previous
//
#include <hip/hip_runtime.h>
#include <math.h>

#define NB 32
#define ND 768
#define NS 196
#define NL 77

typedef __bf16 bf16x8 __attribute__((ext_vector_type(8)));
typedef float f32x4 __attribute__((ext_vector_type(4)));

__device__ __forceinline__ f32x4 mfma16(bf16x8 a, bf16x8 b, f32x4 c) {
  return __builtin_amdgcn_mfma_f32_16x16x32_bf16(a, b, c, 0, 0, 0);
}

#define GLOAD16(gp, lp)                                          \
  __builtin_amdgcn_global_load_lds(                              \
      (const __attribute__((address_space(1))) void*)(gp),       \
      (__attribute__((address_space(3))) void*)(lp), 16, 0, 0)

// Workspace (bf16 elems):
//   txf: [i][24 dk][5 lt][2 pl][512]  = 3,932,160
//   cTf: [j][13 S][24 dk][2 pl][512]  = 10,223,616
//   Gf : [j][13 S][7 kt][2 pl][512]   = 2,981,888
// All MFMA operand streams fragment-contiguous: one wave-load = 1KB contiguous.

// ===================== prep_all: tx-fragments | ctx->frag transpose | lens+norms =====================
__global__ __launch_bounds__(256) void prep_all_kernel(
    const float* __restrict__ text_local,
    const float* __restrict__ img_local,
    const float* __restrict__ img_global,
    const float* __restrict__ text_global,
    const int* __restrict__ amask,
    __bf16* __restrict__ txf, __bf16* __restrict__ cTf,
    float* __restrict__ n1ws, int* __restrict__ lenws,
    float* __restrict__ invni, float* __restrict__ invnt) {
  const int bid = blockIdx.x;
  const int t = threadIdx.x;
  __shared__ float tile[64][213];  // 54.5 KB transpose staging

  if (bid < 960) {
    // ---- text fragments: txf[i][dk][lt][pl][512] ----
    int tau = bid * 256 + t;            // 32*24*5*64
    int i = tau / 7680;
    int r = tau - i * 7680;
    int dk = r / 320;
    int r2 = r - dk * 320;
    int lt = r2 >> 6, lane = r2 & 63;
    int n16 = lane & 15, g = lane >> 4;
    int l = lt * 16 + n16;
    float v[8];
#pragma unroll
    for (int q = 0; q < 8; ++q) v[q] = 0.f;
    if (l < NL) {
      const float* src = text_local + ((size_t)i * NL + l) * ND + dk * 32 + g * 8;
      float4 a = *(const float4*)src;
      float4 b = *(const float4*)(src + 4);
      v[0] = a.x; v[1] = a.y; v[2] = a.z; v[3] = a.w;
      v[4] = b.x; v[5] = b.y; v[6] = b.z; v[7] = b.w;
    }
    bf16x8 hv, lv;
#pragma unroll
    for (int q = 0; q < 8; ++q) {
      __bf16 h = (__bf16)v[q];
      hv[q] = h;
      lv[q] = (__bf16)(v[q] - (float)h);
    }
    size_t base = ((((size_t)i * 24 + dk) * 5 + lt) * 2) * 512 + (size_t)lane * 8;
    *(bf16x8*)(txf + base) = hv;
    *(bf16x8*)(txf + base + 512) = lv;
  } else if (bid < 1344) {
    // ---- ctx transpose to fragment layout cTf[j][S][dk][pl][512] ----
    const int b2 = bid - 960;
    const int j = b2 / 12, dc = b2 - (b2 / 12) * 12;  // dc covers dk {2dc, 2dc+1}
    const float* src = img_local + ((size_t)j * ND + dc * 64) * NS;
    for (int idx = t; idx < 3136; idx += 256) {  // 64 d-rows * 49 float4 (=196 s)
      int dd = idx / 49, sq = idx - dd * 49;
      float4 v = *(const float4*)(src + (size_t)dd * NS + sq * 4);
      tile[dd][sq * 4 + 0] = v.x;
      tile[dd][sq * 4 + 1] = v.y;
      tile[dd][sq * 4 + 2] = v.z;
      tile[dd][sq * 4 + 3] = v.w;
    }
    __syncthreads();
    for (int idx = t; idx < 1664; idx += 256) {  // 13 S * 2 dd2 * 64 lanes
      int lane = idx & 63;
      int rem = idx >> 6;
      int S = rem >> 1, dd2 = rem & 1;
      int n16 = lane & 15, g = lane >> 4;
      int s = S * 16 + n16;
      bf16x8 hv, lv;
#pragma unroll
      for (int e = 0; e < 8; ++e) {
        float v = (s < NS) ? tile[dd2 * 32 + g * 8 + e][s] : 0.f;
        __bf16 h = (__bf16)v;
        hv[e] = h;
        lv[e] = (__bf16)(v - (float)h);
      }
      int dk = dc * 2 + dd2;
      size_t base = ((((size_t)j * 13 + S) * 24 + dk) * 2) * 512 + (size_t)lane * 8;
      *(bf16x8*)(cTf + base) = hv;
      *(bf16x8*)(cTf + base + 512) = lv;
    }
  } else {
    // ---- lengths + word norms + global-vector norms ----
    const int i = bid - 1344;
    const int lane = t & 63, w = t >> 6;
    __shared__ int slen;
    if (t == 0) slen = 0;
    __syncthreads();
    if (t < NL && amask[i * NL + t] != 0) atomicAdd(&slen, 1);
    for (int l = w; l < NL; l += 4) {
      const float4* p = (const float4*)(text_local + ((size_t)i * NL + l) * ND);
      float s = 0.f;
#pragma unroll
      for (int k = 0; k < 3; ++k) {
        float4 v = p[lane + 64 * k];
        s += v.x * v.x + v.y * v.y + v.z * v.z + v.w * v.w;
      }
#pragma unroll
      for (int off = 32; off; off >>= 1) s += __shfl_xor(s, off);
      if (lane == 0) n1ws[i * 80 + l] = sqrtf(s);
    }
    if (w < 2) {
      const float* src2 = (w == 0) ? (img_global + (size_t)i * ND)
                                   : (text_global + (size_t)i * ND);
      const float4* p = (const float4*)src2;
      float s = 0.f;
#pragma unroll
      for (int k = 0; k < 3; ++k) {
        float4 v = p[lane + 64 * k];
        s += v.x * v.x + v.y * v.y + v.z * v.z + v.w * v.w;
      }
#pragma unroll
      for (int off = 32; off; off >>= 1) s += __shfl_xor(s, off);
      if (lane == 0) {
        float inv = 1.0f / fmaxf(sqrtf(s), 1e-12f);
        if (w == 0) invni[i] = inv; else invnt[i] = inv;
      }
    }
    __syncthreads();
    if (t == 0) lenws[i] = slen;
  }
}

// ===================== per-image Gram, frag-contiguous in AND out =====================
__global__ void gram_kernel(const __bf16* __restrict__ cTf, __bf16* __restrict__ Gf) {
  const int bid = blockIdx.x;  // 32 j * 13 st * 2 ch
  const int j = bid / 26;
  const int rr = bid - j * 26;
  const int st = rr >> 1, ch = rr & 1;
  const int t = threadIdx.x, lane = t & 63, w = t >> 6;
  const int g = lane >> 4, n16 = lane & 15;
  const f32x4 z4 = {0.f, 0.f, 0.f, 0.f};
  f32x4 accG[2];
  accG[0] = z4; accG[1] = z4;
  const int base = ch * 7;
  const int ncols = ch ? 6 : 7;
  const size_t cj = (size_t)j * 13;
  for (int dk = 0; dk < 24; ++dk) {
    size_t ao = ((cj + st) * 24 + dk) * 2 * 512 + (size_t)lane * 8;
    bf16x8 Ah = *(const bf16x8*)(cTf + ao);
    bf16x8 Al = *(const bf16x8*)(cTf + ao + 512);
#pragma unroll
    for (int q = 0; q < 2; ++q) {
      int ntl = w + (q << 2);
      if (ntl < ncols) {
        int nt = base + ntl;
        size_t bo = ((cj + nt) * 24 + dk) * 2 * 512 + (size_t)lane * 8;
        bf16x8 Bh = *(const bf16x8*)(cTf + bo);
        bf16x8 Bl = *(const bf16x8*)(cTf + bo + 512);
        accG[q] = mfma16(Ah, Bh, accG[q]);
        accG[q] = mfma16(Ah, Bl, accG[q]);
        accG[q] = mfma16(Al, Bh, accG[q]);
      }
    }
  }
  // write Gf[j][S=st][kt][pl][lane2][8]: elem (s=st*16+g*4+r, col=nt*16+n16)
#pragma unroll
  for (int q = 0; q < 2; ++q) {
    int ntl = w + (q << 2);
    int nt = base + ntl;
    bool compute = (ntl < ncols);
    bool zfill = (ch == 1 && nt == 13);
    if (compute || zfill) {
#pragma unroll
      for (int r = 0; r < 4; ++r) {
        int col = nt * 16 + n16;
        float v = compute ? accG[q][r] : 0.f;
        __bf16 hi = (__bf16)v;
        __bf16 lo = (__bf16)(v - (float)hi);
        int kt = col >> 5, gg = (col >> 3) & 3, e = col & 7;
        int lane2 = (g * 4 + r) + (gg << 4);
        size_t o = ((((size_t)j * 13 + st) * 7 + kt) * 2) * 512 + (size_t)lane2 * 8 + e;
        Gf[o] = hi;
        Gf[o + 512] = lo;
      }
    }
  }
}

// ===================== global contrastive scores =====================
__global__ void gsc_kernel(const float* __restrict__ img_global,
                           const float* __restrict__ text_global,
                           const float* __restrict__ invni,
                           const float* __restrict__ invnt,
                           float* __restrict__ gscw) {
  const int a = blockIdx.x;
  const int t = threadIdx.x;
  const int lane = t & 63;
  const int w = t >> 6;
  __shared__ __align__(16) float shi[ND];
  if (t < ND / 4) ((float4*)shi)[t] = ((const float4*)(img_global + (size_t)a * ND))[t];
  __syncthreads();
  for (int b = w; b < NB; b += 4) {
    const float4* pt = (const float4*)(text_global + (size_t)b * ND);
    const float4* pi = (const float4*)shi;
    float s = 0.f;
#pragma unroll
    for (int k = 0; k < 3; ++k) {
      float4 x = pi[lane + 64 * k];
      float4 y = pt[lane + 64 * k];
      s += x.x * y.x + x.y * y.y + x.z * y.z + x.w * y.w;
    }
#pragma unroll
    for (int off = 32; off; off >>= 1) s += __shfl_xor(s, off);
    if (lane == 0) gscw[a * NB + b] = s * invni[a] * invnt[b] * 10.0f;
  }
}

// ===================== per-pair fused local loss: gload_lds dbuf B + frag-contiguous A =====================
__global__ __launch_bounds__(256, 3) void pair_kernel(
    const __bf16* __restrict__ txf, const __bf16* __restrict__ cTf,
    const __bf16* __restrict__ Gf,
    const float* __restrict__ n1ws, const int* __restrict__ lenws,
    float* __restrict__ simws) {
  const int t = threadIdx.x;
  // XCD swizzle: 1024 % 8 == 0 -> bijective
  const int wg = ((blockIdx.x & 7) << 7) + (blockIdx.x >> 3);
  const int j = wg >> 5, i = wg & 31;
  const int len = lenws[i];
  const int nlt = (len + 15) >> 4;
  const int lane = t & 63, w = t >> 6;
  const int g = lane >> 4, n16 = lane & 15;
  const int nst = (w == 0) ? 4 : 3;

  // b1 (dbuf B staging, phase 1 only) unions with e2f (phases 2-3)
  __shared__ __align__(16) union {
    __bf16 e2f[7 * 5 * 64 * 8];   // 35840 B
    __bf16 b1[2][5][2][512];      // 20480 B
  } U;
  __shared__ float w12s[80], z2s[80], n2s[80];

  if (t < 80) { w12s[t] = 0.f; z2s[t] = 0.f; n2s[t] = 0.f; }

  const f32x4 z4 = {0.f, 0.f, 0.f, 0.f};
  f32x4 acc[4][5];
#pragma unroll
  for (int q = 0; q < 4; ++q)
#pragma unroll
    for (int lt = 0; lt < 5; ++lt) acc[q][lt] = z4;

  const __bf16* txi = txf + (size_t)i * 24 * 5 * 2 * 512;
  const size_t cj = (size_t)j * 13;
  const int nch = nlt << 1;

  // ---- prologue: stage dk=0 B chunks (async, wave-distributed) ----
  for (int c = w; c < nch; c += 4) {
    int lt = c >> 1, pl = c & 1;
    const __bf16* gp = txi + (((size_t)0 * 5 + lt) * 2 + pl) * 512 + ((size_t)lane << 3);
    GLOAD16(gp, &U.b1[0][lt][pl][0]);
  }
  __syncthreads();

  // ---- phase 1: logits, all 13 S-tiles in one pass ----
#pragma unroll 1
  for (int dk = 0; dk < 24; ++dk) {
    const int cur = dk & 1;
    if (dk < 23) {
      for (int c = w; c < nch; c += 4) {
        int lt = c >> 1, pl = c & 1;
        const __bf16* gp = txi + (((size_t)(dk + 1) * 5 + lt) * 2 + pl) * 512 + ((size_t)lane << 3);
        GLOAD16(gp, &U.b1[cur ^ 1][lt][pl][0]);
      }
    }
    bf16x8 Ah[4], Al[4];
#pragma unroll
    for (int q = 0; q < 4; ++q) {
      if (q < nst) {
        int S = w + (q << 2);
        size_t ao = ((cj + S) * 24 + dk) * 2 * 512 + ((size_t)lane << 3);
        Ah[q] = *(const bf16x8*)(cTf + ao);
        Al[q] = *(const bf16x8*)(cTf + ao + 512);
      }
    }
    __builtin_amdgcn_s_setprio(1);
#pragma unroll
    for (int lt = 0; lt < 5; ++lt) {
      if (lt < nlt) {
        bf16x8 Bh = *(const bf16x8*)&U.b1[cur][lt][0][lane << 3];
        bf16x8 Bl = *(const bf16x8*)&U.b1[cur][lt][1][lane << 3];
#pragma unroll
        for (int q = 0; q < 4; ++q) {
          if (q < nst) {
            acc[q][lt] = mfma16(Ah[q], Bh, acc[q][lt]);
            acc[q][lt] = mfma16(Ah[q], Bl, acc[q][lt]);
            acc[q][lt] = mfma16(Al[q], Bh, acc[q][lt]);
          }
        }
      }
    }
    __builtin_amdgcn_s_setprio(0);
    __syncthreads();
  }

  // ---- zero e2f (b1 dead) ----
  for (int idx = t; idx < 2240; idx += 256)
    ((uint4*)U.e2f)[idx] = make_uint4(0, 0, 0, 0);
  __syncthreads();

  // ---- phase 2: register softmax over l, e2 = exp(4*a1), fold w12/Z2 ----
  float w12loc[5], z2loc[5];
#pragma unroll
  for (int lt = 0; lt < 5; ++lt) { w12loc[lt] = 0.f; z2loc[lt] = 0.f; }
#pragma unroll
  for (int q = 0; q < 4; ++q) {
    if (q < nst) {
      int S = w + (q << 2);
#pragma unroll
      for (int r = 0; r < 4; ++r) {
        int s = S * 16 + g * 4 + r;
        bool srow = (s < NS);
        float m = -1e30f;
#pragma unroll
        for (int lt = 0; lt < 5; ++lt) {
          if (lt < nlt) {
            if ((lt * 16 + n16) < len) m = fmaxf(m, acc[q][lt][r]);
          }
        }
        m = fmaxf(m, __shfl_xor(m, 1));
        m = fmaxf(m, __shfl_xor(m, 2));
        m = fmaxf(m, __shfl_xor(m, 4));
        m = fmaxf(m, __shfl_xor(m, 8));
        float z = 0.f;
        float ev[5];
#pragma unroll
        for (int lt = 0; lt < 5; ++lt) {
          float e = 0.f;
          if (lt < nlt) {
            if ((lt * 16 + n16) < len) e = __expf(acc[q][lt][r] - m);
          }
          ev[lt] = e;
          z += e;
        }
        z += __shfl_xor(z, 1);
        z += __shfl_xor(z, 2);
        z += __shfl_xor(z, 4);
        z += __shfl_xor(z, 8);
        float inv = 4.0f / z;
#pragma unroll
        for (int lt = 0; lt < 5; ++lt) {
          if (lt < nlt) {
            if (((lt * 16 + n16) < len) && srow) {
              float e2 = __expf(ev[lt] * inv);
              w12loc[lt] += e2 * acc[q][lt][r];
              z2loc[lt] += e2;
              int kt = s >> 5, kk = s & 31;
              U.e2f[(((kt * 5) + lt) * 64 + (n16 + ((kk >> 3) << 4))) * 8 + (kk & 7)] = (__bf16)e2;
            }
          }
        }
      }
    }
  }
#pragma unroll
  for (int lt = 0; lt < 5; ++lt) {
    w12loc[lt] += __shfl_xor(w12loc[lt], 16);
    w12loc[lt] += __shfl_xor(w12loc[lt], 32);
    z2loc[lt] += __shfl_xor(z2loc[lt], 16);
    z2loc[lt] += __shfl_xor(z2loc[lt], 32);
  }
  if (lane < 16) {
#pragma unroll
    for (int lt = 0; lt < 5; ++lt) {
      if (lt < nlt) {
        atomicAdd(&w12s[lt * 16 + lane], w12loc[lt]);
        atomicAdd(&z2s[lt * 16 + lane], z2loc[lt]);
      }
    }
  }
  __syncthreads();  // e2f complete

  // ---- phase 3: n2^2 = e2^T G e2 via MFMA, Gf frag-contiguous + kt-prefetch ----
  float n2loc[5];
#pragma unroll
  for (int lt = 0; lt < 5; ++lt) n2loc[lt] = 0.f;
#pragma unroll
  for (int q = 0; q < 4; ++q) {
    if (q < nst) {
      int S = w + (q << 2);
      f32x4 a2[5];
#pragma unroll
      for (int lt = 0; lt < 5; ++lt) a2[lt] = z4;
      const __bf16* gp = Gf + (((size_t)j * 13 + S) * 7) * 2 * 512 + ((size_t)lane << 3);
      bf16x8 GAh = *(const bf16x8*)gp;
      bf16x8 GAl = *(const bf16x8*)(gp + 512);
#pragma unroll
      for (int kt = 0; kt < 7; ++kt) {
        bf16x8 GAhN, GAlN;
        if (kt < 6) {
          GAhN = *(const bf16x8*)(gp + (size_t)(kt + 1) * 1024);
          GAlN = *(const bf16x8*)(gp + (size_t)(kt + 1) * 1024 + 512);
        }
        __builtin_amdgcn_s_setprio(1);
#pragma unroll
        for (int lt = 0; lt < 5; ++lt) {
          if (lt < nlt) {
            bf16x8 Bv = *(const bf16x8*)&U.e2f[(((kt * 5) + lt) * 64 + lane) * 8];
            a2[lt] = mfma16(GAh, Bv, a2[lt]);
            a2[lt] = mfma16(GAl, Bv, a2[lt]);
          }
        }
        __builtin_amdgcn_s_setprio(0);
        if (kt < 6) { GAh = GAhN; GAl = GAlN; }
      }
#pragma unroll
      for (int lt = 0; lt < 5; ++lt) {
        if (lt < nlt) {
#pragma unroll
          for (int r = 0; r < 4; ++r) {
            int s = S * 16 + g * 4 + r;
            int kt = s >> 5, kk = s & 31;
            float e2v = (float)U.e2f[(((kt * 5) + lt) * 64 + (n16 + ((kk >> 3) << 4))) * 8 + (kk & 7)];
            n2loc[lt] += e2v * a2[lt][r];
          }
        }
      }
    }
  }
#pragma unroll
  for (int lt = 0; lt < 5; ++lt) {
    n2loc[lt] += __shfl_xor(n2loc[lt], 16);
    n2loc[lt] += __shfl_xor(n2loc[lt], 32);
  }
  if (lane < 16) {
#pragma unroll
    for (int lt = 0; lt < 5; ++lt) {
      if (lt < nlt) atomicAdd(&n2s[lt * 16 + lane], n2loc[lt]);
    }
  }
  __syncthreads();

  // ---- epilogue: cosine + log-sum-exp ----
  if (t < len) {
    float z2 = z2s[t];
    float w12v = w12s[t] / z2;
    float n2v = sqrtf(n2s[t]) / z2;
    float n1v = n1ws[i * 80 + t];
    float cosv = w12v / fmaxf(n1v * n2v, 1e-8f);
    w12s[t] = __expf(5.0f * cosv);
  }
  __syncthreads();
  if (t == 0) {
    float sum = 0.f;
    for (int l = 0; l < len; ++l) sum += w12s[l];
    simws[i * NB + j] = __logf(sum);
  }
}

// ===================== final cross-entropies =====================
__global__ void loss_kernel(const float* __restrict__ gscw,
                            const float* __restrict__ simws,
                            float* __restrict__ out) {
  const int t = threadIdx.x;
  __shared__ float gs[NB][NB];
  __shared__ float sl[NB][NB];
  __shared__ float parts[4][NB];
  {
    float4 gv = ((const float4*)gscw)[t];
    ((float4*)gs)[t] = gv;
    float4 v = ((const float4*)simws)[t];
    int ii = t >> 3;
    int j0 = (t & 7) * 4;
    sl[j0 + 0][ii] = v.x * 10.0f;
    sl[j0 + 1][ii] = v.y * 10.0f;
    sl[j0 + 2][ii] = v.z * 10.0f;
    sl[j0 + 3][ii] = v.w * 10.0f;
  }
  __syncthreads();
  if (t < NB) {
    float m, z;
    m = -1e30f;
    for (int c = 0; c < NB; ++c) m = fmaxf(m, gs[t][c]);
    z = 0.f;
    for (int c = 0; c < NB; ++c) z += __expf(gs[t][c] - m);
    parts[0][t] = m + __logf(z) - gs[t][t];

    m = -1e30f;
    for (int c = 0; c < NB; ++c) m = fmaxf(m, gs[c][t]);
    z = 0.f;
    for (int c = 0; c < NB; ++c) z += __expf(gs[c][t] - m);
    parts[1][t] = m + __logf(z) - gs[t][t];

    m = -1e30f;
    for (int c = 0; c < NB; ++c) m = fmaxf(m, sl[t][c]);
    z = 0.f;
    for (int c = 0; c < NB; ++c) z += __expf(sl[t][c] - m);
    parts[2][t] = m + __logf(z) - sl[t][t];

    m = -1e30f;
    for (int c = 0; c < NB; ++c) m = fmaxf(m, sl[c][t]);
    z = 0.f;
    for (int c = 0; c < NB; ++c) z += __expf(sl[c][t] - m);
    parts[3][t] = m + __logf(z) - sl[t][t];
  }
  __syncthreads();
  if (t == 0) {
    float s0 = 0.f, s1 = 0.f, s2 = 0.f, s3 = 0.f;
    for (int r = 0; r < NB; ++r) {
      s0 += parts[0][r]; s1 += parts[1][r];
      s2 += parts[2][r]; s3 += parts[3][r];
    }
    out[0] = 0.5f * (s0 + s1) / 32.0f + 0.5f * (s2 + s3) / 32.0f;
  }
}

extern "C" void kernel_launch(void* const* d_in, const int* in_sizes, int n_in,
                              void* d_out, int out_size, void* d_ws, size_t ws_size,
                              hipStream_t stream) {
  (void)in_sizes; (void)n_in; (void)out_size; (void)ws_size;
  const float* img_global  = (const float*)d_in[0];
  const float* img_local   = (const float*)d_in[1];
  const float* text_global = (const float*)d_in[2];
  const float* text_local  = (const float*)d_in[3];
  const int*   amask       = (const int*)d_in[4];

  __bf16* txf = (__bf16*)d_ws;                    // 3,932,160
  __bf16* cTf = txf + (size_t)3932160;            // 10,223,616
  __bf16* Gf  = cTf + (size_t)10223616;           // 2,981,888
  float* fsm  = (float*)(Gf + (size_t)2981888);
  float* n1ws  = fsm;                              // [32][80]
  float* simws = fsm + 2560;                       // [32][32]
  float* gscw  = fsm + 3584;                       // [32][32]
  float* invni = fsm + 4608;                       // [32]
  float* invnt = fsm + 4640;                       // [32]
  int*   lenws = (int*)(fsm + 4672);               // [32]

  prep_all_kernel<<<1376, 256, 0, stream>>>(text_local, img_local, img_global,
                                            text_global, amask, txf, cTf,
                                            n1ws, lenws, invni, invnt);
  gram_kernel<<<832, 256, 0, stream>>>(cTf, Gf);
  gsc_kernel<<<32, 256, 0, stream>>>(img_global, text_global, invni, invnt, gscw);
  pair_kernel<<<1024, 256, 0, stream>>>(txf, cTf, Gf, n1ws, lenws, simws);
  loss_kernel<<<1, 256, 0, stream>>>(gscw, simws, (float*)d_out);
}